// Round 11
// baseline (469.511 us; speedup 1.0000x reference)
//
#include <hip/hip_runtime.h>
#include <hip/hip_bf16.h>
#include <math.h>

// Shapes: B=4, C=192, H=W=128, window 16 -> 256 windows of 256 tokens, 6 heads x 32
#define HWC 16384   // 128*128
#define CCH 192
#define LDA 200     // bf16 elems per LDS row (192 + 8 pad; 400 B, 16B-aligned rows)

typedef __attribute__((ext_vector_type(8))) short short8x;
typedef __attribute__((ext_vector_type(4))) float f32x4;

__device__ __forceinline__ float b2f(unsigned int u){
  union { unsigned int i; float f; } x; x.i = (u & 0xffffu) << 16; return x.f;
}
__device__ __forceinline__ unsigned short f2b(float f){
  union { float f; unsigned int i; } x; x.f = f;
  unsigned int r = x.i + 0x7FFFu + ((x.i >> 16) & 1u);   // RNE
  return (unsigned short)(r >> 16);
}
__device__ __forceinline__ unsigned int cvt_pk_bf16(float a, float b){
  unsigned int r;
  asm("v_cvt_pk_bf16_f32 %0, %1, %2" : "=v"(r) : "v"(a), "v"(b));
  return r;   // low16 = bf16(a), high16 = bf16(b)
}
__device__ __forceinline__ float exp2_fast(float x){
  float r;
  asm("v_exp_f32 %0, %1" : "=v"(r) : "v"(x));   // D = 2^S0 (gfx950 VOP1)
  return r;
}
__device__ __forceinline__ float gelu_exact(float v){
  return 0.5f * v * (1.0f + erff(v * 0.70710678118654752440f));
}

// ------- weight prep: bf16 casts + depthwise-weight transpose [26][192] -----
__global__ __launch_bounds__(256) void cast_w_kernel(
    const float* __restrict__ qkvw, const float* __restrict__ projw,
    const float* __restrict__ p1w,  const float* __restrict__ pww,
    const float* __restrict__ p2w,  const float* __restrict__ dww,
    const float* __restrict__ ddw,
    unsigned short* __restrict__ wq,  unsigned short* __restrict__ wprj,
    unsigned short* __restrict__ wp1, unsigned short* __restrict__ wpa,
    unsigned short* __restrict__ wp2, float* __restrict__ dwt,
    float* __restrict__ ddt)
{
  int i = blockIdx.x*256 + threadIdx.x;
  if (i < 110592) wq[i] = f2b(qkvw[i]);
  if (i < 36864){
    wprj[i] = f2b(projw[i]);
    wp1[i]  = f2b(p1w[i]);
    wpa[i]  = f2b(pww[i]);
    wp2[i]  = f2b(p2w[i]);
  }
  if (i < 4992){
    int t = i / 192, c = i - t*192;
    dwt[i] = (t < 25) ? dww[c*25 + t] : 0.0f;
    ddt[i] = (t < 25) ? ddw[c*25 + t] : 0.0f;
  }
}

// ------- transpose x: NCHW f32 -> NHWC f32 (residual) + NHWC bf16 -----------
__global__ __launch_bounds__(256) void tx_kernel(
    const float* __restrict__ in, float* __restrict__ xt32,
    unsigned short* __restrict__ x16)
{
  __shared__ float xs[CCH*68];
  const int tid = threadIdx.x;
  const int pix0 = blockIdx.x * 64;
  const int bb = pix0 >> 14;
  const int hw0 = pix0 & (HWC-1);
  const long base = (long)bb * CCH * HWC + hw0;
  #pragma unroll 8
  for (int i=0;i<48;i++){
    int idx = tid + i*256;
    int ci = idx >> 6, pix = idx & 63;
    xs[ci*68 + pix] = in[base + (long)ci*HWC + pix];
  }
  __syncthreads();
  #pragma unroll 8
  for (int i=0;i<48;i++){
    int idx = tid + i*256;
    int pix = idx / 192, ci = idx - pix*192;
    float v = xs[ci*68 + pix];
    long g = (long)(pix0 + pix)*CCH + ci;
    xt32[g] = v;
    x16[g]  = f2b(v);
  }
}

// ---- fused proj_1 + GELU + pointwise: Y = gelu(X@W1^T+b1); A = Y@WA^T+ba ---
// One staging of X; Y repacked into the same LDS buffer for GEMM-2.
__global__ __launch_bounds__(256, 3) void pw01_mfma(
    const unsigned short* __restrict__ x16,   // [65536][192] bf16
    const unsigned short* __restrict__ w1,    // [192][192] bf16
    const float* __restrict__ b1,
    const unsigned short* __restrict__ wa,    // [192][192] bf16
    const float* __restrict__ ba,
    unsigned short* __restrict__ y16,         // out [65536][192]
    unsigned short* __restrict__ a16)         // out [65536][192]
{
  __shared__ unsigned short sA[128*LDA];      // 51200 B
  const int tid = threadIdx.x;
  const int m0 = blockIdx.x * 128;
  #pragma unroll
  for (int i=0;i<12;i++){
    int idx = tid + i*256;
    int row = idx / 24, oct = idx - row*24;
    uint4 v = *(const uint4*)(x16 + (long)(m0+row)*CCH + oct*8);
    *(uint4*)&sA[row*LDA + oct*8] = v;
  }
  __syncthreads();
  const int wv = tid >> 6, lane = tid & 63;
  const int wm = (wv & 1) * 64;               // pix offset in tile
  const int wn = (wv >> 1) * 96;              // co offset
  const int l15 = lane & 15, q = lane >> 4;
  f32x4 acc[4][6];
  #pragma unroll
  for (int mi=0;mi<4;mi++)
    #pragma unroll
    for (int ni=0;ni<6;ni++) acc[mi][ni] = (f32x4){0.f,0.f,0.f,0.f};
  #pragma unroll
  for (int kk=0; kk<6; kk++){
    const int k0 = kk*32;
    short8x af[4], bf[6];
    #pragma unroll
    for (int mi=0; mi<4; mi++)
      af[mi] = *(const short8x*)&sA[(wm + mi*16 + l15)*LDA + k0 + q*8];
    #pragma unroll
    for (int ni=0; ni<6; ni++)
      bf[ni] = *(const short8x*)(w1 + (long)(wn + ni*16 + l15)*CCH + k0 + q*8);
    #pragma unroll
    for (int mi=0; mi<4; mi++)
      #pragma unroll
      for (int ni=0; ni<6; ni++)
        acc[mi][ni] = __builtin_amdgcn_mfma_f32_16x16x32_bf16(af[mi], bf[ni], acc[mi][ni], 0,0,0);
  }
  float bv[6];
  #pragma unroll
  for (int ni=0; ni<6; ni++) bv[ni] = b1[wn + ni*16 + l15];
  __syncthreads();                            // all X reads done before overwrite
  #pragma unroll
  for (int mi=0; mi<4; mi++){
    #pragma unroll
    for (int r=0; r<4; r++){
      int pixl = wm + mi*16 + q*4 + r;
      long gp = (long)(m0 + pixl)*CCH + wn;
      #pragma unroll
      for (int ni=0; ni<6; ni++){
        unsigned short us = f2b(gelu_exact(acc[mi][ni][r] + bv[ni]));
        y16[gp + ni*16 + l15] = us;
        sA[pixl*LDA + wn + ni*16 + l15] = us;
      }
    }
  }
  __syncthreads();                            // Y tile fully in LDS
  #pragma unroll
  for (int mi=0;mi<4;mi++)
    #pragma unroll
    for (int ni=0;ni<6;ni++) acc[mi][ni] = (f32x4){0.f,0.f,0.f,0.f};
  #pragma unroll
  for (int kk=0; kk<6; kk++){
    const int k0 = kk*32;
    short8x af[4], bf[6];
    #pragma unroll
    for (int mi=0; mi<4; mi++)
      af[mi] = *(const short8x*)&sA[(wm + mi*16 + l15)*LDA + k0 + q*8];
    #pragma unroll
    for (int ni=0; ni<6; ni++)
      bf[ni] = *(const short8x*)(wa + (long)(wn + ni*16 + l15)*CCH + k0 + q*8);
    #pragma unroll
    for (int mi=0; mi<4; mi++)
      #pragma unroll
      for (int ni=0; ni<6; ni++)
        acc[mi][ni] = __builtin_amdgcn_mfma_f32_16x16x32_bf16(af[mi], bf[ni], acc[mi][ni], 0,0,0);
  }
  #pragma unroll
  for (int ni=0; ni<6; ni++) bv[ni] = ba[wn + ni*16 + l15];
  #pragma unroll
  for (int mi=0; mi<4; mi++){
    #pragma unroll
    for (int r=0; r<4; r++){
      long gp = (long)(m0 + wm + mi*16 + q*4 + r)*CCH + wn;
      #pragma unroll
      for (int ni=0; ni<6; ni++)
        a16[gp + ni*16 + l15] = f2b(acc[mi][ni][r] + bv[ni]);
    }
  }
}

// ------- pointwise 1x1 conv via MFMA, NHWC bf16 (MODE 2 only used) ---------
// MODE 2: y2 = (in0*in1) @ W^T + b + xres; LN over C -> z bf16 (fused)
template<int MODE>
__global__ __launch_bounds__(256, 3) void pw_mfma(
    const unsigned short* __restrict__ in0,   // [65536][192] bf16
    const unsigned short* __restrict__ in1,   // [65536][192] bf16 (MODE2)
    const unsigned short* __restrict__ w16,   // [192][192] bf16
    const float* __restrict__ bias,
    const float* __restrict__ xres,           // [65536][192] f32 (MODE2)
    const float* __restrict__ gam, const float* __restrict__ bet,
    unsigned short* __restrict__ out16)
{
  __shared__ unsigned short sA[128*LDA];      // 51200 B
  __shared__ float reds[128*2], reds2[128*2]; // LN cross-wave partials
  const int tid = threadIdx.x;
  const int m0 = blockIdx.x * 128;
  // stage A (product for MODE2)
  #pragma unroll
  for (int i=0;i<12;i++){
    int idx = tid + i*256;
    int row = idx / 24, oct = idx - row*24;
    long g = (long)(m0+row)*CCH + oct*8;
    uint4 vy = *(const uint4*)(in0 + g);
    if (MODE == 2){
      uint4 va = *(const uint4*)(in1 + g);
      unsigned int yy[4] = {vy.x, vy.y, vy.z, vy.w};
      unsigned int aa[4] = {va.x, va.y, va.z, va.w};
      unsigned int rr[4];
      #pragma unroll
      for (int wq2=0; wq2<4; wq2++){
        float lo = b2f(yy[wq2]) * b2f(aa[wq2]);
        float hi = b2f(yy[wq2] >> 16) * b2f(aa[wq2] >> 16);
        rr[wq2] = (unsigned int)f2b(lo) | ((unsigned int)f2b(hi) << 16);
      }
      uint4 vp; vp.x=rr[0]; vp.y=rr[1]; vp.z=rr[2]; vp.w=rr[3];
      *(uint4*)&sA[row*LDA + oct*8] = vp;
    } else {
      *(uint4*)&sA[row*LDA + oct*8] = vy;
    }
  }
  __syncthreads();
  const int wv = tid >> 6, lane = tid & 63;
  const int wm = (wv & 1) * 64;               // pix offset in tile
  const int wn = (wv >> 1) * 96;              // co offset
  const int l15 = lane & 15, q = lane >> 4;
  f32x4 acc[4][6];
  #pragma unroll
  for (int mi=0;mi<4;mi++)
    #pragma unroll
    for (int ni=0;ni<6;ni++) acc[mi][ni] = (f32x4){0.f,0.f,0.f,0.f};
  #pragma unroll
  for (int kk=0; kk<6; kk++){
    const int k0 = kk*32;
    short8x af[4], bf[6];
    #pragma unroll
    for (int mi=0; mi<4; mi++)
      af[mi] = *(const short8x*)&sA[(wm + mi*16 + l15)*LDA + k0 + q*8];
    #pragma unroll
    for (int ni=0; ni<6; ni++)
      bf[ni] = *(const short8x*)(w16 + (long)(wn + ni*16 + l15)*CCH + k0 + q*8);
    #pragma unroll
    for (int mi=0; mi<4; mi++)
      #pragma unroll
      for (int ni=0; ni<6; ni++)
        acc[mi][ni] = __builtin_amdgcn_mfma_f32_16x16x32_bf16(af[mi], bf[ni], acc[mi][ni], 0,0,0);
  }
  float bv[6];
  #pragma unroll
  for (int ni=0; ni<6; ni++) bv[ni] = bias[wn + ni*16 + l15];

  if (MODE != 2){
    #pragma unroll
    for (int mi=0; mi<4; mi++){
      #pragma unroll
      for (int r=0; r<4; r++){
        long gp = (long)(m0 + wm + mi*16 + q*4 + r)*CCH + wn;
        #pragma unroll
        for (int ni=0; ni<6; ni++){
          float v = acc[mi][ni][r] + bv[ni];
          if (MODE == 0) v = gelu_exact(v);
          out16[gp + ni*16 + l15] = f2b(v);
        }
      }
    }
  } else {
    const int slot = wv >> 1;
    #pragma unroll
    for (int mi=0; mi<4; mi++){
      #pragma unroll
      for (int r=0; r<4; r++){
        int pixl = wm + mi*16 + q*4 + r;
        long gp = (long)(m0 + pixl)*CCH + wn;
        float s = 0.f, s2 = 0.f;
        #pragma unroll
        for (int ni=0; ni<6; ni++){
          float v = acc[mi][ni][r] + bv[ni] + xres[gp + ni*16 + l15];
          acc[mi][ni][r] = v;
          s += v; s2 = fmaf(v, v, s2);
        }
        s  += __shfl_xor(s, 1);  s  += __shfl_xor(s, 2);
        s  += __shfl_xor(s, 4);  s  += __shfl_xor(s, 8);
        s2 += __shfl_xor(s2, 1); s2 += __shfl_xor(s2, 2);
        s2 += __shfl_xor(s2, 4); s2 += __shfl_xor(s2, 8);
        if (l15 == 0){ reds[pixl*2 + slot] = s; reds2[pixl*2 + slot] = s2; }
      }
    }
    __syncthreads();
    #pragma unroll
    for (int mi=0; mi<4; mi++){
      #pragma unroll
      for (int r=0; r<4; r++){
        int pixl = wm + mi*16 + q*4 + r;
        long gp = (long)(m0 + pixl)*CCH + wn;
        float st  = reds[pixl*2] + reds[pixl*2+1];
        float s2t = reds2[pixl*2] + reds2[pixl*2+1];
        float mu = st * (1.0f/192.0f);
        float var = s2t * (1.0f/192.0f) - mu*mu;
        float rs = rsqrtf(var + 1e-5f);
        #pragma unroll
        for (int ni=0; ni<6; ni++){
          int co = wn + ni*16 + l15;
          float z = (acc[mi][ni][r] - mu) * rs * gam[co] + bet[co];
          out16[gp + ni*16 + l15] = f2b(z);
        }
      }
    }
  }
}

// ------- depthwise 5x5 conv, LDS-tiled + ZERO-PADDED: 32x32 px x 8 ch -------
template<int PAD, int DIL>
__global__ __launch_bounds__(256) void dw_tile(
    const unsigned short* __restrict__ in16, const float* __restrict__ wT, // [26][192]
    const float* __restrict__ bias, unsigned short* __restrict__ out16)
{
  constexpr int R = 32 + 2*PAD;             // 36 (dw) or 44 (dd)
  constexpr int NPX = R*R;
  constexpr int NIT = (NPX + 255) / 256;
  __shared__ unsigned short sIn[NPX*8];     // 20736 B / 30976 B
  const int bid = blockIdx.x;               // grid = 1536
  const int t_lo = bid & 7, rest = bid >> 3;
  const int c8 = rest % 24, t_hi = rest / 24;
  const int tile = t_lo + 8*t_hi;           // 0..63 (4 batch x 4 ty x 4 tx)
  const int b = tile >> 4, ty = (tile >> 2) & 3, tx = tile & 3;
  const int c0 = c8*8;
  const int tid = threadIdx.x;
  const long ibase = (long)b * HWC * CCH;
  const int r0 = ty*32 - PAD, cl0 = tx*32 - PAD;
  #pragma unroll
  for (int j=0; j<NIT; j++){
    int idx = tid + j*256;
    if (idx < NPX){
      int r = idx / R, c = idx - r*R;
      int gr = r0 + r, gc = cl0 + c;
      uint4 val = (uint4){0u,0u,0u,0u};
      if (((unsigned)gr < 128u) & ((unsigned)gc < 128u))
        val = *(const uint4*)(in16 + ibase + (long)(gr*128 + gc)*CCH + c0);
      *(uint4*)&sIn[idx*8] = val;
    }
  }
  __syncthreads();
  const float4 bb0 = *(const float4*)&bias[c0], bb1 = *(const float4*)&bias[c0+4];
  #pragma unroll
  for (int it=0; it<4; it++){
    int o = tid + it*256;
    int orow = o >> 5, ocol = o & 31;
    float acc[8] = {bb0.x, bb0.y, bb0.z, bb0.w, bb1.x, bb1.y, bb1.z, bb1.w};
    #pragma unroll
    for (int kh=0; kh<5; kh++){
      int lr = orow + kh*DIL;
      #pragma unroll
      for (int kw=0; kw<5; kw++){
        int lc = ocol + kw*DIL;
        uint4 xq = *(const uint4*)&sIn[(lr*R + lc)*8];
        const float* wp = wT + (kh*5 + kw)*CCH + c0;    // uniform -> s_load
        float4 w0 = *(const float4*)wp, w1 = *(const float4*)(wp + 4);
        unsigned int uu[4] = {xq.x, xq.y, xq.z, xq.w};
        float wa[8] = {w0.x, w0.y, w0.z, w0.w, w1.x, w1.y, w1.z, w1.w};
        #pragma unroll
        for (int jj=0; jj<8; jj++){
          float xvf = b2f(uu[jj>>1] >> ((jj&1)*16));
          acc[jj] = fmaf(wa[jj], xvf, acc[jj]);
        }
      }
    }
    int gr = ty*32 + orow, gc = tx*32 + ocol;
    unsigned int rr[4];
    #pragma unroll
    for (int wq2=0; wq2<4; wq2++)
      rr[wq2] = (unsigned int)f2b(acc[wq2*2]) | ((unsigned int)f2b(acc[wq2*2+1]) << 16);
    uint4 ov; ov.x=rr[0]; ov.y=rr[1]; ov.z=rr[2]; ov.w=rr[3];
    *(uint4*)(out16 + ibase + (long)(gr*128 + gc)*CCH + c0) = ov;
  }
}

// ---- qkv GEMM via MFMA -> RAW q/k/v bf16 in d-interleaved window layout ----
__global__ __launch_bounds__(256, 3) void qkv_fused(
    const unsigned short* __restrict__ z16,   // [65536][192] bf16
    const unsigned short* __restrict__ w16,   // [576][192] bf16
    const float* __restrict__ qb, const float* __restrict__ vb,
    unsigned short* __restrict__ qkvb)
{
  __shared__ unsigned short sA[128*LDA];      // 51200 B
  const int tid = threadIdx.x;
  const int m0 = blockIdx.x * 128;            // pixel base
  #pragma unroll
  for (int i=0;i<12;i++){
    int idx = tid + i*256;
    int row = idx / 24, oct = idx - row*24;
    uint4 v = *(const uint4*)(z16 + (long)(m0+row)*CCH + oct*8);
    *(uint4*)&sA[row*LDA + oct*8] = v;
  }
  __syncthreads();
  const int wv = tid >> 6, lane = tid & 63;
  const int wm = (wv & 1) * 64;               // pix offset in tile
  const int wn = (wv >> 1) * 96;              // co offset in slice (3 heads/wave)
  const int l15 = lane & 15, q = lane >> 4;
  const int head0 = wn >> 5;                  // 0 or 3
  int winm[4], tokb[4];
  #pragma unroll
  for (int mi=0;mi<4;mi++){
    int pb = m0 + wm + mi*16;
    int hw = pb & (HWC-1);
    int row = hw >> 7, col = hw & 127;
    winm[mi] = (pb>>14)*64 + (row>>4)*8 + (col>>4);
    tokb[mi] = (row & 15) * 16;               // col&15 == 0 (16-aligned)
  }
  #pragma unroll
  for (int s=0; s<3; s++){
    const unsigned short* wbase = w16 + (long)(s*192)*CCH;
    f32x4 acc[4][6];
    #pragma unroll
    for (int mi=0;mi<4;mi++)
      #pragma unroll
      for (int ni=0;ni<6;ni++) acc[mi][ni] = (f32x4){0.f,0.f,0.f,0.f};
    #pragma unroll
    for (int kk=0; kk<6; kk++){
      const int k0 = kk*32;
      short8x af[4], bf[6];
      #pragma unroll
      for (int mi=0; mi<4; mi++)
        af[mi] = *(const short8x*)&sA[(wm + mi*16 + l15)*LDA + k0 + q*8];
      #pragma unroll
      for (int ni=0; ni<6; ni++)
        bf[ni] = *(const short8x*)(wbase + (long)(wn + ni*16 + l15)*CCH + k0 + q*8);
      #pragma unroll
      for (int mi=0; mi<4; mi++)
        #pragma unroll
        for (int ni=0; ni<6; ni++)
          acc[mi][ni] = __builtin_amdgcn_mfma_f32_16x16x32_bf16(af[mi], bf[ni], acc[mi][ni], 0,0,0);
    }
    float bvv[6];
    #pragma unroll
    for (int ni=0;ni<6;ni++){
      int co = wn + ni*16 + l15;
      bvv[ni] = (s==0) ? qb[co] : ((s==2) ? vb[co] : 0.0f);
    }
    unsigned short* dst = qkvb + (long)s * 12582912;
    #pragma unroll
    for (int mi=0; mi<4; mi++){
      long obase = (long)winm[mi]*49152 + (long)tokb[mi]*32 + l15*2;
      #pragma unroll
      for (int r=0; r<4; r++){
        long ob = obase + (q*4 + r)*32;
        #pragma unroll
        for (int hp=0; hp<3; hp++){
          unsigned int u = (unsigned int)f2b(acc[mi][hp*2][r]   + bvv[hp*2])
                         | ((unsigned int)f2b(acc[mi][hp*2+1][r] + bvv[hp*2+1]) << 16);
          *(unsigned int*)&dst[ob + (long)(head0 + hp)*8192] = u;
        }
      }
    }
  }
}

// ---------------- CPB MLP: table(961,2) -> (961,6) --------------------------
__device__ __forceinline__ float cpb_coord(int a){
  float r = ((float)a - 15.0f) * (8.0f/15.0f);
  float t = log2f(fabsf(r) + 1.0f) * (1.0f/3.0f);
  return (r < 0.f) ? -t : t;
}
__global__ __launch_bounds__(128) void cpb_mlp_kernel(
    const float* __restrict__ w1, const float* __restrict__ b1,
    const float* __restrict__ w2, float* __restrict__ tbl6)
{
  int e = blockIdx.x;
  int a = e / 31, bb = e - a*31;
  float t0 = cpb_coord(a), t1 = cpb_coord(bb);
  float p[6] = {0,0,0,0,0,0};
  for (int hh = threadIdx.x; hh < 512; hh += 128){
    float hid = t0*w1[hh*2] + t1*w1[hh*2+1] + b1[hh];
    hid = fmaxf(hid, 0.0f);
    #pragma unroll
    for (int hd=0; hd<6; hd++) p[hd] = fmaf(hid, w2[hd*512 + hh], p[hd]);
  }
  __shared__ float red[6][128];
  #pragma unroll
  for (int hd=0; hd<6; hd++) red[hd][threadIdx.x] = p[hd];
  __syncthreads();
  if (threadIdx.x < 6){
    float sum = 0.f;
    for (int i=0;i<128;i++) sum += red[threadIdx.x][i];
    tbl6[e*6 + threadIdx.x] = sum;
  }
}
// expand to PAIRED bias table: bias2[h][i][kt][l15] = float2{
//   f(i, kt*32+l15), f(i, kt*32+16+l15) }  where f = (16*sigmoid-16)*log2e.
// One aligned 8B load in attn delivers both e0/e1 biases for a lane.
__global__ __launch_bounds__(256) void cpb_expand_kernel(
    const float* __restrict__ tbl6, float2* __restrict__ bias2)
{
  int idx = blockIdx.x*256 + threadIdx.x;      // < 6*256*8*16 = 196608
  int h = idx >> 15;
  int rem = idx & 32767;
  int i = rem >> 7;
  int rem2 = rem & 127;
  int kt = rem2 >> 4, l15 = rem2 & 15;
  int j0 = kt*32 + l15, j1 = j0 + 16;
  int dy0 = (i>>4) - (j0>>4) + 15, dx0 = (i&15) - (j0&15) + 15;
  int dy1 = (i>>4) - (j1>>4) + 15, dx1 = (i&15) - (j1&15) + 15;
  float v0 = tbl6[(dy0*31+dx0)*6 + h];
  float v1 = tbl6[(dy1*31+dx1)*6 + h];
  float2 o;
  o.x = (16.0f / (1.0f + __expf(-v0)) - 16.0f) * 1.4426950408889634f;
  o.y = (16.0f / (1.0f + __expf(-v1)) - 16.0f) * 1.4426950408889634f;
  bias2[idx] = o;
}

// ------------- windowed cosine attention via MFMA, block=(win, head) --------
// inputs RAW bf16 [win][head][tok][pos32]; k-norm folded into LDS K, q-norm
// (incl. logit scale and log2e) applied per entry; bias paired float2 and
// software-pipelined one kt ahead (registers are free: occupancy is LDS-bound).
#define KSP 40    // ks/ps row stride (shorts): 80 B, 16B-aligned
#define VTP 264   // vt row stride (shorts): 528 B, 16B-aligned
__global__ __launch_bounds__(256) void attn_mfma(
    const unsigned short* __restrict__ qkvb, const float2* __restrict__ bias2,
    const float* __restrict__ ls,
    unsigned short* __restrict__ aout)
{
  __shared__ unsigned short ks[256*KSP];      // 20480 B  khat bf16 [key][pos]
  __shared__ unsigned short vt[32*VTP];       // 16896 B  v bf16 [pos][key-slot]
  __shared__ unsigned short ps[4][64*KSP];    // 20480 B  per-wave P (slot cols)
  __shared__ float qinvs[256];                // 1024 B   per-token sc*log2e/|q|
  const int win = blockIdx.x, h = blockIdx.y;
  const int t = threadIdx.x;
  const long base = ((long)(win*6 + h)) << 13;   // *8192 (256 tok * 32 pos)
  const unsigned short* Qg = qkvb + base;
  const unsigned short* Kg = Qg + 12582912;
  const unsigned short* Vg = Kg + 12582912;
  const float sc = __expf(fminf(ls[h], 4.60517018598809136804f));  // ln(100)

  { // ---- stage khat = k/|k| (normalized during staging) + q inverse norms --
    union { uint4 v4[4]; unsigned int u[16]; } kb, ko, qv;
    const unsigned short* kr = Kg + t*32;
    #pragma unroll
    for (int o=0;o<4;o++) kb.v4[o] = *(const uint4*)(kr + o*8);
    float sk = 0.f;
    #pragma unroll
    for (int i=0;i<16;i++){
      float lo = b2f(kb.u[i]), hi = b2f(kb.u[i]>>16);
      sk = fmaf(lo, lo, sk); sk = fmaf(hi, hi, sk);
    }
    float kinv = 1.0f / fmaxf(sqrtf(sk), 1e-12f);
    #pragma unroll
    for (int i=0;i<16;i++)
      ko.u[i] = cvt_pk_bf16(b2f(kb.u[i])*kinv, b2f(kb.u[i]>>16)*kinv);
    #pragma unroll
    for (int o=0;o<4;o++) *(uint4*)&ks[t*KSP + o*8] = ko.v4[o];

    const unsigned short* qr = Qg + t*32;
    #pragma unroll
    for (int o=0;o<4;o++) qv.v4[o] = *(const uint4*)(qr + o*8);
    float sq = 0.f;
    #pragma unroll
    for (int i=0;i<16;i++){
      float lo = b2f(qv.u[i]), hi = b2f(qv.u[i]>>16);
      sq = fmaf(lo, lo, sq); sq = fmaf(hi, hi, sq);
    }
    qinvs[t] = sc * 1.4426950408889634f / fmaxf(sqrtf(sq), 1e-12f);
  }
  { // ---- stage v transposed (coalesced row load + LDS scatter), slot cols --
    const int kt = t >> 5, j = t & 31;
    const int col = kt*32 + ((j & 15)*2 + (j >> 4));   // key-slot permutation
    union { unsigned short u[32]; uint4 v4[4]; } vp;
    const unsigned short* vr = Vg + t*32;
    #pragma unroll
    for (int o=0;o<4;o++) vp.v4[o] = *(const uint4*)(vr + o*8);
    #pragma unroll
    for (int d=0; d<32; d++) vt[d*VTP + col] = vp.u[d];
  }
  const int wv = t >> 6, lane = t & 63;
  const int l15 = lane & 15, q = lane >> 4;
  short8x qa[4];
  #pragma unroll
  for (int mi=0; mi<4; mi++)                   // Q fragments straight from global
    qa[mi] = *(const short8x*)(Qg + (wv*64 + mi*16 + l15)*32 + q*8);
  __syncthreads();

  float4 qiv[4];
  #pragma unroll
  for (int mi=0; mi<4; mi++)
    qiv[mi] = *(const float4*)&qinvs[wv*64 + mi*16 + q*4];

  f32x4 oacc[4][2], lsum[4];
  #pragma unroll
  for (int mi=0;mi<4;mi++){
    oacc[mi][0] = (f32x4){0.f,0.f,0.f,0.f};
    oacc[mi][1] = (f32x4){0.f,0.f,0.f,0.f};
    lsum[mi]    = (f32x4){0.f,0.f,0.f,0.f};
  }
  const float2* bias_h2 = bias2 + ((long)h << 15);   // h*32768 float2
  unsigned short* myps = ps[wv];

  // prefetch kt=0 bias pairs
  float2 bp[4][4];
  #pragma unroll
  for (int mi=0; mi<4; mi++)
    #pragma unroll
    for (int r=0; r<4; r++)
      bp[mi][r] = bias_h2[(wv*64 + mi*16 + q*4 + r)*128 + l15];

  #pragma unroll
  for (int kt=0; kt<8; kt++){
    const int k0 = kt*32;
    short8x kb0 = *(const short8x*)&ks[(k0 + l15)*KSP + q*8];
    short8x kb1 = *(const short8x*)&ks[(k0 + 16 + l15)*KSP + q*8];
    f32x4 s[4][2];
    __builtin_amdgcn_s_setprio(1);
    #pragma unroll
    for (int mi=0; mi<4; mi++){
      f32x4 z0 = (f32x4){0.f,0.f,0.f,0.f};
      s[mi][0] = __builtin_amdgcn_mfma_f32_16x16x32_bf16(qa[mi], kb0, z0, 0,0,0);
      s[mi][1] = __builtin_amdgcn_mfma_f32_16x16x32_bf16(qa[mi], kb1, z0, 0,0,0);
    }
    __builtin_amdgcn_s_setprio(0);
    #pragma unroll
    for (int mi=0; mi<4; mi++){
      const float* qivp = (const float*)&qiv[mi];
      #pragma unroll
      for (int r=0; r<4; r++){
        float qr2 = qivp[r];
        float e0 = exp2_fast(fminf(fmaf(s[mi][0][r], qr2, bp[mi][r].x), 43.f));
        float e1 = exp2_fast(fminf(fmaf(s[mi][1][r], qr2, bp[mi][r].y), 43.f));
        lsum[mi][r] += e0 + e1;
        *(unsigned int*)&myps[(mi*16 + q*4 + r)*KSP + l15*2] = cvt_pk_bf16(e0, e1);
      }
    }
    // prefetch next kt's bias pairs: latency hides under PV + next QK^T MFMAs
    if (kt < 7){
      #pragma unroll
      for (int mi=0; mi<4; mi++)
        #pragma unroll
        for (int r=0; r<4; r++)
          bp[mi][r] = bias_h2[(wv*64 + mi*16 + q*4 + r)*128 + (kt+1)*16 + l15];
    }
    short8x vb0 = *(const short8x*)&vt[(l15)*VTP      + k0 + q*8];
    short8x vb1 = *(const short8x*)&vt[(16 + l15)*VTP + k0 + q*8];
    __builtin_amdgcn_s_setprio(1);
    #pragma unroll
    for (int mi=0; mi<4; mi++){
      short8x pa = *(const short8x*)&myps[(mi*16 + l15)*KSP + q*8];
      oacc[mi][0] = __builtin_amdgcn_mfma_f32_16x16x32_bf16(pa, vb0, oacc[mi][0], 0,0,0);
      oacc[mi][1] = __builtin_amdgcn_mfma_f32_16x16x32_bf16(pa, vb1, oacc[mi][1], 0,0,0);
    }
    __builtin_amdgcn_s_setprio(0);
  }
  #pragma unroll
  for (int mi=0; mi<4; mi++){
    #pragma unroll
    for (int r=0; r<4; r++){
      float v = lsum[mi][r];
      v += __shfl_xor(v, 1);
      v += __shfl_xor(v, 2);
      v += __shfl_xor(v, 4);
      v += __shfl_xor(v, 8);
      lsum[mi][r] = v;
    }
  }
  // oacc columns are positions; invert d-interleave: pos p -> d = (p>>1)+((p&1)<<4)
  const int dperm = (l15 >> 1) + ((l15 & 1) << 4);
  const int bb = win >> 6, wy = (win >> 3) & 7, wx = win & 7;
  #pragma unroll
  for (int mi=0; mi<4; mi++){
    #pragma unroll
    for (int r=0; r<4; r++){
      int rowq = wv*64 + mi*16 + q*4 + r;
      int pixo = bb*HWC + (wy*16 + (rowq>>4))*128 + wx*16 + (rowq&15);
      float inv = 1.0f / lsum[mi][r];
      aout[(long)pixo*CCH + h*32 + dperm]     = f2b(oacc[mi][0][r]*inv);
      aout[(long)pixo*CCH + h*32 + dperm + 8] = f2b(oacc[mi][1][r]*inv);
    }
  }
}

// ------- proj GEMM via MFMA: aout16 @ WP^T + b -> NCHW f32 (coalesced) ------
__global__ __launch_bounds__(256, 3) void proj_mfma(
    const unsigned short* __restrict__ a16,   // [65536][192] bf16
    const unsigned short* __restrict__ w16,   // [192][192] bf16
    const float* __restrict__ bias,
    float* __restrict__ outp)                 // NCHW f32
{
  __shared__ unsigned short sB[128*LDA];
  const int tid = threadIdx.x;
  const int n0 = blockIdx.x * 128;            // pixel base
  #pragma unroll
  for (int i=0;i<12;i++){
    int idx = tid + i*256;
    int row = idx / 24, oct = idx - row*24;
    uint4 v = *(const uint4*)(a16 + (long)(n0+row)*CCH + oct*8);
    *(uint4*)&sB[row*LDA + oct*8] = v;
  }
  __syncthreads();
  const int wv = tid >> 6, lane = tid & 63;
  const int wm = (wv & 1) * 96;               // co offset
  const int wn = (wv >> 1) * 64;              // pix offset in tile
  const int l15 = lane & 15, q = lane >> 4;
  f32x4 acc[6][4];
  #pragma unroll
  for (int mi=0;mi<6;mi++)
    #pragma unroll
    for (int ni=0;ni<4;ni++) acc[mi][ni] = (f32x4){0.f,0.f,0.f,0.f};
  #pragma unroll
  for (int kk=0; kk<6; kk++){
    const int k0 = kk*32;
    short8x af[6], bf[4];
    #pragma unroll
    for (int mi=0; mi<6; mi++)
      af[mi] = *(const short8x*)(w16 + (long)(wm + mi*16 + l15)*CCH + k0 + q*8);
    #pragma unroll
    for (int ni=0; ni<4; ni++)
      bf[ni] = *(const short8x*)&sB[(wn + ni*16 + l15)*LDA + k0 + q*8];
    #pragma unroll
    for (int mi=0; mi<6; mi++)
      #pragma unroll
      for (int ni=0; ni<4; ni++)
        acc[mi][ni] = __builtin_amdgcn_mfma_f32_16x16x32_bf16(af[mi], bf[ni], acc[mi][ni], 0,0,0);
  }
  #pragma unroll
  for (int mi=0; mi<6; mi++){
    #pragma unroll
    for (int r=0; r<4; r++){
      int co = wm + mi*16 + q*4 + r;
      float bv = bias[co];
      #pragma unroll
      for (int ni=0; ni<4; ni++){
        int pix = n0 + wn + ni*16 + l15;
        int b = pix >> 14, hw = pix & (HWC-1);
        outp[((long)b*CCH + co)*HWC + hw] = acc[mi][ni][r] + bv;
      }
    }
  }
}

// ---------------------------------------------------------------------------
extern "C" void kernel_launch(void* const* d_in, const int* in_sizes, int n_in,
                              void* d_out, int out_size, void* d_ws, size_t ws_size,
                              hipStream_t stream)
{
  const float* x       = (const float*)d_in[0];
  const float* p1_w    = (const float*)d_in[1];
  const float* p1_b    = (const float*)d_in[2];
  const float* pw_w    = (const float*)d_in[3];
  const float* pw_b    = (const float*)d_in[4];
  const float* dw_w    = (const float*)d_in[5];
  const float* dw_b    = (const float*)d_in[6];
  const float* dd_w    = (const float*)d_in[7];
  const float* dd_b    = (const float*)d_in[8];
  const float* p2_w    = (const float*)d_in[9];
  const float* p2_b    = (const float*)d_in[10];
  const float* ln_g    = (const float*)d_in[11];
  const float* ln_b    = (const float*)d_in[12];
  const float* qkv_w   = (const float*)d_in[13];
  const float* q_bias  = (const float*)d_in[14];
  const float* v_bias  = (const float*)d_in[15];
  const float* lscale  = (const float*)d_in[16];
  const float* cpb_w1  = (const float*)d_in[17];
  const float* cpb_b1  = (const float*)d_in[18];
  const float* cpb_w2  = (const float*)d_in[19];
  const float* proj_w  = (const float*)d_in[20];
  const float* proj_b  = (const float*)d_in[21];

  float* ws = (float*)d_ws;
  const long A = 12582912L;           // 4*192*128*128
  unsigned short* X16  = (unsigned short*)ws;                 // [0, A/2)
  unsigned short* Y16  = (unsigned short*)(ws + A/2);         // [A/2, A)
  unsigned short* A16  = (unsigned short*)(ws + A);           // [A, 1.5A)
  unsigned short* T16  = (unsigned short*)(ws + A + A/2);     // [1.5A, 2A)
  float* XT32 = ws + 2*A;                                     // [2A, 3A)
  unsigned short* QKVB = (unsigned short*)ws;                 // [0, 1.5A) after convs
  unsigned short* Z16  = (unsigned short*)(ws + 3*A);         // [3A, 3.5A)
  unsigned short* AO16 = Z16;                                 // attn out reuses z16
  float* DWT = ws + 3*A + A/2;                                // 26*192 = 4992
  float* DDT = DWT + 4992;                                    // 26*192 = 4992
  unsigned short* WQ   = (unsigned short*)(DDT + 4992);       // 110592
  unsigned short* WPRJ = WQ + 110592;                         // 36864
  unsigned short* WP1  = WPRJ + 36864;
  unsigned short* WPA  = WP1 + 36864;
  unsigned short* WP2  = WPA + 36864;
  float* RB = ws + 4*A;               // paired bias table (6*256*8*16 float2)
  float* T6 = RB + 393216;            // cpb mlp out (961*6)

  // weight prep + CPB bias table (independent of main chain)
  cast_w_kernel<<<432, 256, 0, stream>>>(qkv_w, proj_w, p1_w, pw_w, p2_w, dw_w, dd_w,
                                         WQ, WPRJ, WP1, WPA, WP2, DWT, DDT);
  cpb_mlp_kernel<<<961, 128, 0, stream>>>(cpb_w1, cpb_b1, cpb_w2, T6);
  cpb_expand_kernel<<<768, 256, 0, stream>>>(T6, (float2*)RB);

  // x -> NHWC (f32 residual + bf16)
  tx_kernel<<<1024, 256, 0, stream>>>(x, XT32, X16);

  // VAB conv block: fused proj_1+GELU+pointwise, then LDS-tiled depthwise pair
  pw01_mfma<<<512, 256, 0, stream>>>(X16, WP1, p1_b, WPA, pw_b, Y16, A16);
  dw_tile<2,1><<<1536, 256, 0, stream>>>(A16, DWT, dw_b, T16);
  dw_tile<6,3><<<1536, 256, 0, stream>>>(T16, DDT, dd_b, A16);
  // proj_2 + residual + fused LayerNorm -> z16
  pw_mfma<2><<<512, 256, 0, stream>>>(Y16, A16, WP2, p2_b, XT32, ln_g, ln_b, Z16);

  // qkv GEMM -> raw bf16 window layout, single pass (s-loop inside)
  qkv_fused<<<512, 256, 0, stream>>>(Z16, WQ, q_bias, v_bias, QKVB);

  // window attention on MFMA (paired+pipelined bias, staged khat norms)
  attn_mfma<<<dim3(256, 6), 256, 0, stream>>>(QKVB, (const float2*)RB, lscale, AO16);

  // projection on MFMA + window-reverse -> f32 NCHW
  proj_mfma<<<512, 256, 0, stream>>>(AO16, WPRJ, proj_b, (float*)d_out);
}

// Round 12
// 453.122 us; speedup vs baseline: 1.0362x; 1.0362x over previous
//
#include <hip/hip_runtime.h>
#include <hip/hip_bf16.h>
#include <math.h>

// Shapes: B=4, C=192, H=W=128, window 16 -> 256 windows of 256 tokens, 6 heads x 32
#define HWC 16384   // 128*128
#define CCH 192
#define LDA 200     // bf16 elems per LDS row (192 + 8 pad; 400 B, 16B-aligned rows)

typedef __attribute__((ext_vector_type(8))) short short8x;
typedef __attribute__((ext_vector_type(4))) float f32x4;

__device__ __forceinline__ float b2f(unsigned int u){
  union { unsigned int i; float f; } x; x.i = (u & 0xffffu) << 16; return x.f;
}
__device__ __forceinline__ unsigned short f2b(float f){
  union { float f; unsigned int i; } x; x.f = f;
  unsigned int r = x.i + 0x7FFFu + ((x.i >> 16) & 1u);   // RNE
  return (unsigned short)(r >> 16);
}
__device__ __forceinline__ unsigned int cvt_pk_bf16(float a, float b){
  unsigned int r;
  asm("v_cvt_pk_bf16_f32 %0, %1, %2" : "=v"(r) : "v"(a), "v"(b));
  return r;   // low16 = bf16(a), high16 = bf16(b)
}
__device__ __forceinline__ float exp2_fast(float x){
  float r;
  asm("v_exp_f32 %0, %1" : "=v"(r) : "v"(x));   // D = 2^S0 (gfx950 VOP1)
  return r;
}
__device__ __forceinline__ float gelu_exact(float v){
  return 0.5f * v * (1.0f + erff(v * 0.70710678118654752440f));
}

// ------- weight prep: bf16 casts + depthwise-weight transpose [26][192] -----
__global__ __launch_bounds__(256) void cast_w_kernel(
    const float* __restrict__ qkvw, const float* __restrict__ projw,
    const float* __restrict__ p1w,  const float* __restrict__ pww,
    const float* __restrict__ p2w,  const float* __restrict__ dww,
    const float* __restrict__ ddw,
    unsigned short* __restrict__ wq,  unsigned short* __restrict__ wprj,
    unsigned short* __restrict__ wp1, unsigned short* __restrict__ wpa,
    unsigned short* __restrict__ wp2, float* __restrict__ dwt,
    float* __restrict__ ddt)
{
  int i = blockIdx.x*256 + threadIdx.x;
  if (i < 110592) wq[i] = f2b(qkvw[i]);
  if (i < 36864){
    wprj[i] = f2b(projw[i]);
    wp1[i]  = f2b(p1w[i]);
    wpa[i]  = f2b(pww[i]);
    wp2[i]  = f2b(p2w[i]);
  }
  if (i < 4992){
    int t = i / 192, c = i - t*192;
    dwt[i] = (t < 25) ? dww[c*25 + t] : 0.0f;
    ddt[i] = (t < 25) ? ddw[c*25 + t] : 0.0f;
  }
}

// ------- transpose x: NCHW f32 -> NHWC f32 (residual) + NHWC bf16 -----------
__global__ __launch_bounds__(256) void tx_kernel(
    const float* __restrict__ in, float* __restrict__ xt32,
    unsigned short* __restrict__ x16)
{
  __shared__ float xs[CCH*68];
  const int tid = threadIdx.x;
  const int pix0 = blockIdx.x * 64;
  const int bb = pix0 >> 14;
  const int hw0 = pix0 & (HWC-1);
  const long base = (long)bb * CCH * HWC + hw0;
  #pragma unroll 8
  for (int i=0;i<48;i++){
    int idx = tid + i*256;
    int ci = idx >> 6, pix = idx & 63;
    xs[ci*68 + pix] = in[base + (long)ci*HWC + pix];
  }
  __syncthreads();
  #pragma unroll 8
  for (int i=0;i<48;i++){
    int idx = tid + i*256;
    int pix = idx / 192, ci = idx - pix*192;
    float v = xs[ci*68 + pix];
    long g = (long)(pix0 + pix)*CCH + ci;
    xt32[g] = v;
    x16[g]  = f2b(v);
  }
}

// ---- fused proj_1 + GELU + pointwise: Y = gelu(X@W1^T+b1); A = Y@WA^T+ba ---
// One staging of X; Y repacked into the same LDS buffer for GEMM-2.
__global__ __launch_bounds__(256, 3) void pw01_mfma(
    const unsigned short* __restrict__ x16,   // [65536][192] bf16
    const unsigned short* __restrict__ w1,    // [192][192] bf16
    const float* __restrict__ b1,
    const unsigned short* __restrict__ wa,    // [192][192] bf16
    const float* __restrict__ ba,
    unsigned short* __restrict__ y16,         // out [65536][192]
    unsigned short* __restrict__ a16)         // out [65536][192]
{
  __shared__ unsigned short sA[128*LDA];      // 51200 B
  const int tid = threadIdx.x;
  const int m0 = blockIdx.x * 128;
  #pragma unroll
  for (int i=0;i<12;i++){
    int idx = tid + i*256;
    int row = idx / 24, oct = idx - row*24;
    uint4 v = *(const uint4*)(x16 + (long)(m0+row)*CCH + oct*8);
    *(uint4*)&sA[row*LDA + oct*8] = v;
  }
  __syncthreads();
  const int wv = tid >> 6, lane = tid & 63;
  const int wm = (wv & 1) * 64;               // pix offset in tile
  const int wn = (wv >> 1) * 96;              // co offset
  const int l15 = lane & 15, q = lane >> 4;
  f32x4 acc[4][6];
  #pragma unroll
  for (int mi=0;mi<4;mi++)
    #pragma unroll
    for (int ni=0;ni<6;ni++) acc[mi][ni] = (f32x4){0.f,0.f,0.f,0.f};
  #pragma unroll
  for (int kk=0; kk<6; kk++){
    const int k0 = kk*32;
    short8x af[4], bf[6];
    #pragma unroll
    for (int mi=0; mi<4; mi++)
      af[mi] = *(const short8x*)&sA[(wm + mi*16 + l15)*LDA + k0 + q*8];
    #pragma unroll
    for (int ni=0; ni<6; ni++)
      bf[ni] = *(const short8x*)(w1 + (long)(wn + ni*16 + l15)*CCH + k0 + q*8);
    #pragma unroll
    for (int mi=0; mi<4; mi++)
      #pragma unroll
      for (int ni=0; ni<6; ni++)
        acc[mi][ni] = __builtin_amdgcn_mfma_f32_16x16x32_bf16(af[mi], bf[ni], acc[mi][ni], 0,0,0);
  }
  float bv[6];
  #pragma unroll
  for (int ni=0; ni<6; ni++) bv[ni] = b1[wn + ni*16 + l15];
  __syncthreads();                            // all X reads done before overwrite
  #pragma unroll
  for (int mi=0; mi<4; mi++){
    #pragma unroll
    for (int r=0; r<4; r++){
      int pixl = wm + mi*16 + q*4 + r;
      long gp = (long)(m0 + pixl)*CCH + wn;
      #pragma unroll
      for (int ni=0; ni<6; ni++){
        unsigned short us = f2b(gelu_exact(acc[mi][ni][r] + bv[ni]));
        y16[gp + ni*16 + l15] = us;
        sA[pixl*LDA + wn + ni*16 + l15] = us;
      }
    }
  }
  __syncthreads();                            // Y tile fully in LDS
  #pragma unroll
  for (int mi=0;mi<4;mi++)
    #pragma unroll
    for (int ni=0;ni<6;ni++) acc[mi][ni] = (f32x4){0.f,0.f,0.f,0.f};
  #pragma unroll
  for (int kk=0; kk<6; kk++){
    const int k0 = kk*32;
    short8x af[4], bf[6];
    #pragma unroll
    for (int mi=0; mi<4; mi++)
      af[mi] = *(const short8x*)&sA[(wm + mi*16 + l15)*LDA + k0 + q*8];
    #pragma unroll
    for (int ni=0; ni<6; ni++)
      bf[ni] = *(const short8x*)(wa + (long)(wn + ni*16 + l15)*CCH + k0 + q*8);
    #pragma unroll
    for (int mi=0; mi<4; mi++)
      #pragma unroll
      for (int ni=0; ni<6; ni++)
        acc[mi][ni] = __builtin_amdgcn_mfma_f32_16x16x32_bf16(af[mi], bf[ni], acc[mi][ni], 0,0,0);
  }
  #pragma unroll
  for (int ni=0; ni<6; ni++) bv[ni] = ba[wn + ni*16 + l15];
  #pragma unroll
  for (int mi=0; mi<4; mi++){
    #pragma unroll
    for (int r=0; r<4; r++){
      long gp = (long)(m0 + wm + mi*16 + q*4 + r)*CCH + wn;
      #pragma unroll
      for (int ni=0; ni<6; ni++)
        a16[gp + ni*16 + l15] = f2b(acc[mi][ni][r] + bv[ni]);
    }
  }
}

// ------- pointwise 1x1 conv via MFMA, NHWC bf16 (MODE 2 only used) ---------
// MODE 2: y2 = (in0*in1) @ W^T + b + xres; LN over C -> z bf16 (fused)
template<int MODE>
__global__ __launch_bounds__(256, 3) void pw_mfma(
    const unsigned short* __restrict__ in0,   // [65536][192] bf16
    const unsigned short* __restrict__ in1,   // [65536][192] bf16 (MODE2)
    const unsigned short* __restrict__ w16,   // [192][192] bf16
    const float* __restrict__ bias,
    const float* __restrict__ xres,           // [65536][192] f32 (MODE2)
    const float* __restrict__ gam, const float* __restrict__ bet,
    unsigned short* __restrict__ out16)
{
  __shared__ unsigned short sA[128*LDA];      // 51200 B
  __shared__ float reds[128*2], reds2[128*2]; // LN cross-wave partials
  const int tid = threadIdx.x;
  const int m0 = blockIdx.x * 128;
  // stage A (product for MODE2)
  #pragma unroll
  for (int i=0;i<12;i++){
    int idx = tid + i*256;
    int row = idx / 24, oct = idx - row*24;
    long g = (long)(m0+row)*CCH + oct*8;
    uint4 vy = *(const uint4*)(in0 + g);
    if (MODE == 2){
      uint4 va = *(const uint4*)(in1 + g);
      unsigned int yy[4] = {vy.x, vy.y, vy.z, vy.w};
      unsigned int aa[4] = {va.x, va.y, va.z, va.w};
      unsigned int rr[4];
      #pragma unroll
      for (int wq2=0; wq2<4; wq2++){
        float lo = b2f(yy[wq2]) * b2f(aa[wq2]);
        float hi = b2f(yy[wq2] >> 16) * b2f(aa[wq2] >> 16);
        rr[wq2] = (unsigned int)f2b(lo) | ((unsigned int)f2b(hi) << 16);
      }
      uint4 vp; vp.x=rr[0]; vp.y=rr[1]; vp.z=rr[2]; vp.w=rr[3];
      *(uint4*)&sA[row*LDA + oct*8] = vp;
    } else {
      *(uint4*)&sA[row*LDA + oct*8] = vy;
    }
  }
  __syncthreads();
  const int wv = tid >> 6, lane = tid & 63;
  const int wm = (wv & 1) * 64;               // pix offset in tile
  const int wn = (wv >> 1) * 96;              // co offset
  const int l15 = lane & 15, q = lane >> 4;
  f32x4 acc[4][6];
  #pragma unroll
  for (int mi=0;mi<4;mi++)
    #pragma unroll
    for (int ni=0;ni<6;ni++) acc[mi][ni] = (f32x4){0.f,0.f,0.f,0.f};
  #pragma unroll
  for (int kk=0; kk<6; kk++){
    const int k0 = kk*32;
    short8x af[4], bf[6];
    #pragma unroll
    for (int mi=0; mi<4; mi++)
      af[mi] = *(const short8x*)&sA[(wm + mi*16 + l15)*LDA + k0 + q*8];
    #pragma unroll
    for (int ni=0; ni<6; ni++)
      bf[ni] = *(const short8x*)(w16 + (long)(wn + ni*16 + l15)*CCH + k0 + q*8);
    #pragma unroll
    for (int mi=0; mi<4; mi++)
      #pragma unroll
      for (int ni=0; ni<6; ni++)
        acc[mi][ni] = __builtin_amdgcn_mfma_f32_16x16x32_bf16(af[mi], bf[ni], acc[mi][ni], 0,0,0);
  }
  float bv[6];
  #pragma unroll
  for (int ni=0; ni<6; ni++) bv[ni] = bias[wn + ni*16 + l15];

  if (MODE != 2){
    #pragma unroll
    for (int mi=0; mi<4; mi++){
      #pragma unroll
      for (int r=0; r<4; r++){
        long gp = (long)(m0 + wm + mi*16 + q*4 + r)*CCH + wn;
        #pragma unroll
        for (int ni=0; ni<6; ni++){
          float v = acc[mi][ni][r] + bv[ni];
          if (MODE == 0) v = gelu_exact(v);
          out16[gp + ni*16 + l15] = f2b(v);
        }
      }
    }
  } else {
    const int slot = wv >> 1;
    #pragma unroll
    for (int mi=0; mi<4; mi++){
      #pragma unroll
      for (int r=0; r<4; r++){
        int pixl = wm + mi*16 + q*4 + r;
        long gp = (long)(m0 + pixl)*CCH + wn;
        float s = 0.f, s2 = 0.f;
        #pragma unroll
        for (int ni=0; ni<6; ni++){
          float v = acc[mi][ni][r] + bv[ni] + xres[gp + ni*16 + l15];
          acc[mi][ni][r] = v;
          s += v; s2 = fmaf(v, v, s2);
        }
        s  += __shfl_xor(s, 1);  s  += __shfl_xor(s, 2);
        s  += __shfl_xor(s, 4);  s  += __shfl_xor(s, 8);
        s2 += __shfl_xor(s2, 1); s2 += __shfl_xor(s2, 2);
        s2 += __shfl_xor(s2, 4); s2 += __shfl_xor(s2, 8);
        if (l15 == 0){ reds[pixl*2 + slot] = s; reds2[pixl*2 + slot] = s2; }
      }
    }
    __syncthreads();
    #pragma unroll
    for (int mi=0; mi<4; mi++){
      #pragma unroll
      for (int r=0; r<4; r++){
        int pixl = wm + mi*16 + q*4 + r;
        long gp = (long)(m0 + pixl)*CCH + wn;
        float st  = reds[pixl*2] + reds[pixl*2+1];
        float s2t = reds2[pixl*2] + reds2[pixl*2+1];
        float mu = st * (1.0f/192.0f);
        float var = s2t * (1.0f/192.0f) - mu*mu;
        float rs = rsqrtf(var + 1e-5f);
        #pragma unroll
        for (int ni=0; ni<6; ni++){
          int co = wn + ni*16 + l15;
          float z = (acc[mi][ni][r] - mu) * rs * gam[co] + bet[co];
          out16[gp + ni*16 + l15] = f2b(z);
        }
      }
    }
  }
}

// ------- depthwise 5x5 conv, LDS-tiled + ZERO-PADDED: 32x32 px x 8 ch -------
template<int PAD, int DIL>
__global__ __launch_bounds__(256) void dw_tile(
    const unsigned short* __restrict__ in16, const float* __restrict__ wT, // [26][192]
    const float* __restrict__ bias, unsigned short* __restrict__ out16)
{
  constexpr int R = 32 + 2*PAD;             // 36 (dw) or 44 (dd)
  constexpr int NPX = R*R;
  constexpr int NIT = (NPX + 255) / 256;
  __shared__ unsigned short sIn[NPX*8];     // 20736 B / 30976 B
  const int bid = blockIdx.x;               // grid = 1536
  const int t_lo = bid & 7, rest = bid >> 3;
  const int c8 = rest % 24, t_hi = rest / 24;
  const int tile = t_lo + 8*t_hi;           // 0..63 (4 batch x 4 ty x 4 tx)
  const int b = tile >> 4, ty = (tile >> 2) & 3, tx = tile & 3;
  const int c0 = c8*8;
  const int tid = threadIdx.x;
  const long ibase = (long)b * HWC * CCH;
  const int r0 = ty*32 - PAD, cl0 = tx*32 - PAD;
  #pragma unroll
  for (int j=0; j<NIT; j++){
    int idx = tid + j*256;
    if (idx < NPX){
      int r = idx / R, c = idx - r*R;
      int gr = r0 + r, gc = cl0 + c;
      uint4 val = (uint4){0u,0u,0u,0u};
      if (((unsigned)gr < 128u) & ((unsigned)gc < 128u))
        val = *(const uint4*)(in16 + ibase + (long)(gr*128 + gc)*CCH + c0);
      *(uint4*)&sIn[idx*8] = val;
    }
  }
  __syncthreads();
  const float4 bb0 = *(const float4*)&bias[c0], bb1 = *(const float4*)&bias[c0+4];
  #pragma unroll
  for (int it=0; it<4; it++){
    int o = tid + it*256;
    int orow = o >> 5, ocol = o & 31;
    float acc[8] = {bb0.x, bb0.y, bb0.z, bb0.w, bb1.x, bb1.y, bb1.z, bb1.w};
    #pragma unroll
    for (int kh=0; kh<5; kh++){
      int lr = orow + kh*DIL;
      #pragma unroll
      for (int kw=0; kw<5; kw++){
        int lc = ocol + kw*DIL;
        uint4 xq = *(const uint4*)&sIn[(lr*R + lc)*8];
        const float* wp = wT + (kh*5 + kw)*CCH + c0;    // uniform -> s_load
        float4 w0 = *(const float4*)wp, w1 = *(const float4*)(wp + 4);
        unsigned int uu[4] = {xq.x, xq.y, xq.z, xq.w};
        float wa[8] = {w0.x, w0.y, w0.z, w0.w, w1.x, w1.y, w1.z, w1.w};
        #pragma unroll
        for (int jj=0; jj<8; jj++){
          float xvf = b2f(uu[jj>>1] >> ((jj&1)*16));
          acc[jj] = fmaf(wa[jj], xvf, acc[jj]);
        }
      }
    }
    int gr = ty*32 + orow, gc = tx*32 + ocol;
    unsigned int rr[4];
    #pragma unroll
    for (int wq2=0; wq2<4; wq2++)
      rr[wq2] = (unsigned int)f2b(acc[wq2*2]) | ((unsigned int)f2b(acc[wq2*2+1]) << 16);
    uint4 ov; ov.x=rr[0]; ov.y=rr[1]; ov.z=rr[2]; ov.w=rr[3];
    *(uint4*)(out16 + ibase + (long)(gr*128 + gc)*CCH + c0) = ov;
  }
}

// ---- qkv GEMM via MFMA -> RAW q/k/v bf16 in d-interleaved window layout ----
__global__ __launch_bounds__(256, 3) void qkv_fused(
    const unsigned short* __restrict__ z16,   // [65536][192] bf16
    const unsigned short* __restrict__ w16,   // [576][192] bf16
    const float* __restrict__ qb, const float* __restrict__ vb,
    unsigned short* __restrict__ qkvb)
{
  __shared__ unsigned short sA[128*LDA];      // 51200 B
  const int tid = threadIdx.x;
  const int m0 = blockIdx.x * 128;            // pixel base
  #pragma unroll
  for (int i=0;i<12;i++){
    int idx = tid + i*256;
    int row = idx / 24, oct = idx - row*24;
    uint4 v = *(const uint4*)(z16 + (long)(m0+row)*CCH + oct*8);
    *(uint4*)&sA[row*LDA + oct*8] = v;
  }
  __syncthreads();
  const int wv = tid >> 6, lane = tid & 63;
  const int wm = (wv & 1) * 64;               // pix offset in tile
  const int wn = (wv >> 1) * 96;              // co offset in slice (3 heads/wave)
  const int l15 = lane & 15, q = lane >> 4;
  const int head0 = wn >> 5;                  // 0 or 3
  int winm[4], tokb[4];
  #pragma unroll
  for (int mi=0;mi<4;mi++){
    int pb = m0 + wm + mi*16;
    int hw = pb & (HWC-1);
    int row = hw >> 7, col = hw & 127;
    winm[mi] = (pb>>14)*64 + (row>>4)*8 + (col>>4);
    tokb[mi] = (row & 15) * 16;               // col&15 == 0 (16-aligned)
  }
  #pragma unroll
  for (int s=0; s<3; s++){
    const unsigned short* wbase = w16 + (long)(s*192)*CCH;
    f32x4 acc[4][6];
    #pragma unroll
    for (int mi=0;mi<4;mi++)
      #pragma unroll
      for (int ni=0;ni<6;ni++) acc[mi][ni] = (f32x4){0.f,0.f,0.f,0.f};
    #pragma unroll
    for (int kk=0; kk<6; kk++){
      const int k0 = kk*32;
      short8x af[4], bf[6];
      #pragma unroll
      for (int mi=0; mi<4; mi++)
        af[mi] = *(const short8x*)&sA[(wm + mi*16 + l15)*LDA + k0 + q*8];
      #pragma unroll
      for (int ni=0; ni<6; ni++)
        bf[ni] = *(const short8x*)(wbase + (long)(wn + ni*16 + l15)*CCH + k0 + q*8);
      #pragma unroll
      for (int mi=0; mi<4; mi++)
        #pragma unroll
        for (int ni=0; ni<6; ni++)
          acc[mi][ni] = __builtin_amdgcn_mfma_f32_16x16x32_bf16(af[mi], bf[ni], acc[mi][ni], 0,0,0);
    }
    float bvv[6];
    #pragma unroll
    for (int ni=0;ni<6;ni++){
      int co = wn + ni*16 + l15;
      bvv[ni] = (s==0) ? qb[co] : ((s==2) ? vb[co] : 0.0f);
    }
    unsigned short* dst = qkvb + (long)s * 12582912;
    #pragma unroll
    for (int mi=0; mi<4; mi++){
      long obase = (long)winm[mi]*49152 + (long)tokb[mi]*32 + l15*2;
      #pragma unroll
      for (int r=0; r<4; r++){
        long ob = obase + (q*4 + r)*32;
        #pragma unroll
        for (int hp=0; hp<3; hp++){
          unsigned int u = (unsigned int)f2b(acc[mi][hp*2][r]   + bvv[hp*2])
                         | ((unsigned int)f2b(acc[mi][hp*2+1][r] + bvv[hp*2+1]) << 16);
          *(unsigned int*)&dst[ob + (long)(head0 + hp)*8192] = u;
        }
      }
    }
  }
}

// ---------------- CPB MLP: table(961,2) -> (961,6) --------------------------
__device__ __forceinline__ float cpb_coord(int a){
  float r = ((float)a - 15.0f) * (8.0f/15.0f);
  float t = log2f(fabsf(r) + 1.0f) * (1.0f/3.0f);
  return (r < 0.f) ? -t : t;
}
__global__ __launch_bounds__(128) void cpb_mlp_kernel(
    const float* __restrict__ w1, const float* __restrict__ b1,
    const float* __restrict__ w2, float* __restrict__ tbl6)
{
  int e = blockIdx.x;
  int a = e / 31, bb = e - a*31;
  float t0 = cpb_coord(a), t1 = cpb_coord(bb);
  float p[6] = {0,0,0,0,0,0};
  for (int hh = threadIdx.x; hh < 512; hh += 128){
    float hid = t0*w1[hh*2] + t1*w1[hh*2+1] + b1[hh];
    hid = fmaxf(hid, 0.0f);
    #pragma unroll
    for (int hd=0; hd<6; hd++) p[hd] = fmaf(hid, w2[hd*512 + hh], p[hd]);
  }
  __shared__ float red[6][128];
  #pragma unroll
  for (int hd=0; hd<6; hd++) red[hd][threadIdx.x] = p[hd];
  __syncthreads();
  if (threadIdx.x < 6){
    float sum = 0.f;
    for (int i=0;i<128;i++) sum += red[threadIdx.x][i];
    tbl6[e*6 + threadIdx.x] = sum;
  }
}
// expand to PAIRED bias table: bias2[h][i][kt][l15] = float2{
//   f(i, kt*32+l15), f(i, kt*32+16+l15) }  where f = (16*sigmoid-16)*log2e.
// One aligned 8B load in attn delivers both e0/e1 biases for a lane.
__global__ __launch_bounds__(256) void cpb_expand_kernel(
    const float* __restrict__ tbl6, float2* __restrict__ bias2)
{
  int idx = blockIdx.x*256 + threadIdx.x;      // < 6*256*8*16 = 196608
  int h = idx >> 15;
  int rem = idx & 32767;
  int i = rem >> 7;
  int rem2 = rem & 127;
  int kt = rem2 >> 4, l15 = rem2 & 15;
  int j0 = kt*32 + l15, j1 = j0 + 16;
  int dy0 = (i>>4) - (j0>>4) + 15, dx0 = (i&15) - (j0&15) + 15;
  int dy1 = (i>>4) - (j1>>4) + 15, dx1 = (i&15) - (j1&15) + 15;
  float v0 = tbl6[(dy0*31+dx0)*6 + h];
  float v1 = tbl6[(dy1*31+dx1)*6 + h];
  float2 o;
  o.x = (16.0f / (1.0f + __expf(-v0)) - 16.0f) * 1.4426950408889634f;
  o.y = (16.0f / (1.0f + __expf(-v1)) - 16.0f) * 1.4426950408889634f;
  bias2[idx] = o;
}

// ------------- windowed cosine attention via MFMA, block=(win, head) --------
// inputs RAW bf16 [win][head][tok][pos32]; k-norm folded into LDS K, q-norm
// (incl. logit scale and log2e) applied per entry; bias paired float2 loaded
// JUST-IN-TIME (round-11's register-held prefetch dropped occupancy 2x: the
// VGPR cost of holding 32 pairs outweighed the latency win).
#define KSP 40    // ks/ps row stride (shorts): 80 B, 16B-aligned
#define VTP 264   // vt row stride (shorts): 528 B, 16B-aligned
__global__ __launch_bounds__(256) void attn_mfma(
    const unsigned short* __restrict__ qkvb, const float2* __restrict__ bias2,
    const float* __restrict__ ls,
    unsigned short* __restrict__ aout)
{
  __shared__ unsigned short ks[256*KSP];      // 20480 B  khat bf16 [key][pos]
  __shared__ unsigned short vt[32*VTP];       // 16896 B  v bf16 [pos][key-slot]
  __shared__ unsigned short ps[4][64*KSP];    // 20480 B  per-wave P (slot cols)
  __shared__ float qinvs[256];                // 1024 B   per-token sc*log2e/|q|
  const int win = blockIdx.x, h = blockIdx.y;
  const int t = threadIdx.x;
  const long base = ((long)(win*6 + h)) << 13;   // *8192 (256 tok * 32 pos)
  const unsigned short* Qg = qkvb + base;
  const unsigned short* Kg = Qg + 12582912;
  const unsigned short* Vg = Kg + 12582912;
  const float sc = __expf(fminf(ls[h], 4.60517018598809136804f));  // ln(100)

  { // ---- stage khat = k/|k| (normalized during staging) + q inverse norms --
    union { uint4 v4[4]; unsigned int u[16]; } kb, ko, qv;
    const unsigned short* kr = Kg + t*32;
    #pragma unroll
    for (int o=0;o<4;o++) kb.v4[o] = *(const uint4*)(kr + o*8);
    float sk = 0.f;
    #pragma unroll
    for (int i=0;i<16;i++){
      float lo = b2f(kb.u[i]), hi = b2f(kb.u[i]>>16);
      sk = fmaf(lo, lo, sk); sk = fmaf(hi, hi, sk);
    }
    float kinv = 1.0f / fmaxf(sqrtf(sk), 1e-12f);
    #pragma unroll
    for (int i=0;i<16;i++)
      ko.u[i] = cvt_pk_bf16(b2f(kb.u[i])*kinv, b2f(kb.u[i]>>16)*kinv);
    #pragma unroll
    for (int o=0;o<4;o++) *(uint4*)&ks[t*KSP + o*8] = ko.v4[o];

    const unsigned short* qr = Qg + t*32;
    #pragma unroll
    for (int o=0;o<4;o++) qv.v4[o] = *(const uint4*)(qr + o*8);
    float sq = 0.f;
    #pragma unroll
    for (int i=0;i<16;i++){
      float lo = b2f(qv.u[i]), hi = b2f(qv.u[i]>>16);
      sq = fmaf(lo, lo, sq); sq = fmaf(hi, hi, sq);
    }
    qinvs[t] = sc * 1.4426950408889634f / fmaxf(sqrtf(sq), 1e-12f);
  }
  { // ---- stage v transposed (coalesced row load + LDS scatter), slot cols --
    const int kt = t >> 5, j = t & 31;
    const int col = kt*32 + ((j & 15)*2 + (j >> 4));   // key-slot permutation
    union { unsigned short u[32]; uint4 v4[4]; } vp;
    const unsigned short* vr = Vg + t*32;
    #pragma unroll
    for (int o=0;o<4;o++) vp.v4[o] = *(const uint4*)(vr + o*8);
    #pragma unroll
    for (int d=0; d<32; d++) vt[d*VTP + col] = vp.u[d];
  }
  const int wv = t >> 6, lane = t & 63;
  const int l15 = lane & 15, q = lane >> 4;
  short8x qa[4];
  #pragma unroll
  for (int mi=0; mi<4; mi++)                   // Q fragments straight from global
    qa[mi] = *(const short8x*)(Qg + (wv*64 + mi*16 + l15)*32 + q*8);
  __syncthreads();

  float4 qiv[4];
  #pragma unroll
  for (int mi=0; mi<4; mi++)
    qiv[mi] = *(const float4*)&qinvs[wv*64 + mi*16 + q*4];

  f32x4 oacc[4][2], lsum[4];
  #pragma unroll
  for (int mi=0;mi<4;mi++){
    oacc[mi][0] = (f32x4){0.f,0.f,0.f,0.f};
    oacc[mi][1] = (f32x4){0.f,0.f,0.f,0.f};
    lsum[mi]    = (f32x4){0.f,0.f,0.f,0.f};
  }
  const float2* bias_h2 = bias2 + ((long)h << 15);   // h*32768 float2
  unsigned short* myps = ps[wv];

  for (int kt=0; kt<8; kt++){
    const int k0 = kt*32;
    short8x kb0 = *(const short8x*)&ks[(k0 + l15)*KSP + q*8];
    short8x kb1 = *(const short8x*)&ks[(k0 + 16 + l15)*KSP + q*8];
    f32x4 s[4][2];
    __builtin_amdgcn_s_setprio(1);
    #pragma unroll
    for (int mi=0; mi<4; mi++){
      f32x4 z0 = (f32x4){0.f,0.f,0.f,0.f};
      s[mi][0] = __builtin_amdgcn_mfma_f32_16x16x32_bf16(qa[mi], kb0, z0, 0,0,0);
      s[mi][1] = __builtin_amdgcn_mfma_f32_16x16x32_bf16(qa[mi], kb1, z0, 0,0,0);
    }
    __builtin_amdgcn_s_setprio(0);
    #pragma unroll
    for (int mi=0; mi<4; mi++){
      const float* qivp = (const float*)&qiv[mi];
      #pragma unroll
      for (int r=0; r<4; r++){
        int rowq = wv*64 + mi*16 + q*4 + r;
        float2 bpr = bias_h2[rowq*128 + kt*16 + l15];   // one 8B load (both biases)
        float qr2 = qivp[r];
        float e0 = exp2_fast(fminf(fmaf(s[mi][0][r], qr2, bpr.x), 43.f));
        float e1 = exp2_fast(fminf(fmaf(s[mi][1][r], qr2, bpr.y), 43.f));
        lsum[mi][r] += e0 + e1;
        *(unsigned int*)&myps[(mi*16 + q*4 + r)*KSP + l15*2] = cvt_pk_bf16(e0, e1);
      }
    }
    short8x vb0 = *(const short8x*)&vt[(l15)*VTP      + k0 + q*8];
    short8x vb1 = *(const short8x*)&vt[(16 + l15)*VTP + k0 + q*8];
    __builtin_amdgcn_s_setprio(1);
    #pragma unroll
    for (int mi=0; mi<4; mi++){
      short8x pa = *(const short8x*)&myps[(mi*16 + l15)*KSP + q*8];
      oacc[mi][0] = __builtin_amdgcn_mfma_f32_16x16x32_bf16(pa, vb0, oacc[mi][0], 0,0,0);
      oacc[mi][1] = __builtin_amdgcn_mfma_f32_16x16x32_bf16(pa, vb1, oacc[mi][1], 0,0,0);
    }
    __builtin_amdgcn_s_setprio(0);
  }
  #pragma unroll
  for (int mi=0; mi<4; mi++){
    #pragma unroll
    for (int r=0; r<4; r++){
      float v = lsum[mi][r];
      v += __shfl_xor(v, 1);
      v += __shfl_xor(v, 2);
      v += __shfl_xor(v, 4);
      v += __shfl_xor(v, 8);
      lsum[mi][r] = v;
    }
  }
  // oacc columns are positions; invert d-interleave: pos p -> d = (p>>1)+((p&1)<<4)
  const int dperm = (l15 >> 1) + ((l15 & 1) << 4);
  const int bb = win >> 6, wy = (win >> 3) & 7, wx = win & 7;
  #pragma unroll
  for (int mi=0; mi<4; mi++){
    #pragma unroll
    for (int r=0; r<4; r++){
      int rowq = wv*64 + mi*16 + q*4 + r;
      int pixo = bb*HWC + (wy*16 + (rowq>>4))*128 + wx*16 + (rowq&15);
      float inv = 1.0f / lsum[mi][r];
      aout[(long)pixo*CCH + h*32 + dperm]     = f2b(oacc[mi][0][r]*inv);
      aout[(long)pixo*CCH + h*32 + dperm + 8] = f2b(oacc[mi][1][r]*inv);
    }
  }
}

// ------- proj GEMM via MFMA: aout16 @ WP^T + b -> NCHW f32 (coalesced) ------
__global__ __launch_bounds__(256, 3) void proj_mfma(
    const unsigned short* __restrict__ a16,   // [65536][192] bf16
    const unsigned short* __restrict__ w16,   // [192][192] bf16
    const float* __restrict__ bias,
    float* __restrict__ outp)                 // NCHW f32
{
  __shared__ unsigned short sB[128*LDA];
  const int tid = threadIdx.x;
  const int n0 = blockIdx.x * 128;            // pixel base
  #pragma unroll
  for (int i=0;i<12;i++){
    int idx = tid + i*256;
    int row = idx / 24, oct = idx - row*24;
    uint4 v = *(const uint4*)(a16 + (long)(n0+row)*CCH + oct*8);
    *(uint4*)&sB[row*LDA + oct*8] = v;
  }
  __syncthreads();
  const int wv = tid >> 6, lane = tid & 63;
  const int wm = (wv & 1) * 96;               // co offset
  const int wn = (wv >> 1) * 64;              // pix offset in tile
  const int l15 = lane & 15, q = lane >> 4;
  f32x4 acc[6][4];
  #pragma unroll
  for (int mi=0;mi<6;mi++)
    #pragma unroll
    for (int ni=0;ni<4;ni++) acc[mi][ni] = (f32x4){0.f,0.f,0.f,0.f};
  #pragma unroll
  for (int kk=0; kk<6; kk++){
    const int k0 = kk*32;
    short8x af[6], bf[4];
    #pragma unroll
    for (int mi=0; mi<6; mi++)
      af[mi] = *(const short8x*)(w16 + (long)(wm + mi*16 + l15)*CCH + k0 + q*8);
    #pragma unroll
    for (int ni=0; ni<4; ni++)
      bf[ni] = *(const short8x*)&sB[(wn + ni*16 + l15)*LDA + k0 + q*8];
    #pragma unroll
    for (int mi=0; mi<6; mi++)
      #pragma unroll
      for (int ni=0; ni<4; ni++)
        acc[mi][ni] = __builtin_amdgcn_mfma_f32_16x16x32_bf16(af[mi], bf[ni], acc[mi][ni], 0,0,0);
  }
  #pragma unroll
  for (int mi=0; mi<6; mi++){
    #pragma unroll
    for (int r=0; r<4; r++){
      int co = wm + mi*16 + q*4 + r;
      float bv = bias[co];
      #pragma unroll
      for (int ni=0; ni<4; ni++){
        int pix = n0 + wn + ni*16 + l15;
        int b = pix >> 14, hw = pix & (HWC-1);
        outp[((long)b*CCH + co)*HWC + hw] = acc[mi][ni][r] + bv;
      }
    }
  }
}

// ---------------------------------------------------------------------------
extern "C" void kernel_launch(void* const* d_in, const int* in_sizes, int n_in,
                              void* d_out, int out_size, void* d_ws, size_t ws_size,
                              hipStream_t stream)
{
  const float* x       = (const float*)d_in[0];
  const float* p1_w    = (const float*)d_in[1];
  const float* p1_b    = (const float*)d_in[2];
  const float* pw_w    = (const float*)d_in[3];
  const float* pw_b    = (const float*)d_in[4];
  const float* dw_w    = (const float*)d_in[5];
  const float* dw_b    = (const float*)d_in[6];
  const float* dd_w    = (const float*)d_in[7];
  const float* dd_b    = (const float*)d_in[8];
  const float* p2_w    = (const float*)d_in[9];
  const float* p2_b    = (const float*)d_in[10];
  const float* ln_g    = (const float*)d_in[11];
  const float* ln_b    = (const float*)d_in[12];
  const float* qkv_w   = (const float*)d_in[13];
  const float* q_bias  = (const float*)d_in[14];
  const float* v_bias  = (const float*)d_in[15];
  const float* lscale  = (const float*)d_in[16];
  const float* cpb_w1  = (const float*)d_in[17];
  const float* cpb_b1  = (const float*)d_in[18];
  const float* cpb_w2  = (const float*)d_in[19];
  const float* proj_w  = (const float*)d_in[20];
  const float* proj_b  = (const float*)d_in[21];

  float* ws = (float*)d_ws;
  const long A = 12582912L;           // 4*192*128*128
  unsigned short* X16  = (unsigned short*)ws;                 // [0, A/2)
  unsigned short* Y16  = (unsigned short*)(ws + A/2);         // [A/2, A)
  unsigned short* A16  = (unsigned short*)(ws + A);           // [A, 1.5A)
  unsigned short* T16  = (unsigned short*)(ws + A + A/2);     // [1.5A, 2A)
  float* XT32 = ws + 2*A;                                     // [2A, 3A)
  unsigned short* QKVB = (unsigned short*)ws;                 // [0, 1.5A) after convs
  unsigned short* Z16  = (unsigned short*)(ws + 3*A);         // [3A, 3.5A)
  unsigned short* AO16 = Z16;                                 // attn out reuses z16
  float* DWT = ws + 3*A + A/2;                                // 26*192 = 4992
  float* DDT = DWT + 4992;                                    // 26*192 = 4992
  unsigned short* WQ   = (unsigned short*)(DDT + 4992);       // 110592
  unsigned short* WPRJ = WQ + 110592;                         // 36864
  unsigned short* WP1  = WPRJ + 36864;
  unsigned short* WPA  = WP1 + 36864;
  unsigned short* WP2  = WPA + 36864;
  float* RB = ws + 4*A;               // paired bias table (6*256*8*16 float2)
  float* T6 = RB + 393216;            // cpb mlp out (961*6)

  // weight prep + CPB bias table (independent of main chain)
  cast_w_kernel<<<432, 256, 0, stream>>>(qkv_w, proj_w, p1_w, pw_w, p2_w, dw_w, dd_w,
                                         WQ, WPRJ, WP1, WPA, WP2, DWT, DDT);
  cpb_mlp_kernel<<<961, 128, 0, stream>>>(cpb_w1, cpb_b1, cpb_w2, T6);
  cpb_expand_kernel<<<768, 256, 0, stream>>>(T6, (float2*)RB);

  // x -> NHWC (f32 residual + bf16)
  tx_kernel<<<1024, 256, 0, stream>>>(x, XT32, X16);

  // VAB conv block: fused proj_1+GELU+pointwise, then LDS-tiled depthwise pair
  pw01_mfma<<<512, 256, 0, stream>>>(X16, WP1, p1_b, WPA, pw_b, Y16, A16);
  dw_tile<2,1><<<1536, 256, 0, stream>>>(A16, DWT, dw_b, T16);
  dw_tile<6,3><<<1536, 256, 0, stream>>>(T16, DDT, dd_b, A16);
  // proj_2 + residual + fused LayerNorm -> z16
  pw_mfma<2><<<512, 256, 0, stream>>>(Y16, A16, WP2, p2_b, XT32, ln_g, ln_b, Z16);

  // qkv GEMM -> raw bf16 window layout, single pass (s-loop inside)
  qkv_fused<<<512, 256, 0, stream>>>(Z16, WQ, q_bias, v_bias, QKVB);

  // window attention on MFMA (paired bias just-in-time, staged khat norms)
  attn_mfma<<<dim3(256, 6), 256, 0, stream>>>(QKVB, (const float2*)RB, lscale, AO16);

  // projection on MFMA + window-reverse -> f32 NCHW
  proj_mfma<<<512, 256, 0, stream>>>(AO16, WPRJ, proj_b, (float*)d_out);
}